// Round 9
// baseline (290.338 us; speedup 1.0000x reference)
//
#include <hip/hip_runtime.h>

// ---------------------------------------------------------------------------
// MultiHeadAttention: x[4,2048,1024] fp32 -> QKV proj -> MHA (16 heads, d=64)
// -> out proj. bf16 MFMA everywhere (fp32 accum), flash attention.
// R12: cooperative mega-kernel FAILED (absmax 0.079): cross-XCD L2 staleness
//   at grid.sync stage boundaries (Guideline-16). Reverted; dispatch-gap
//   hypothesis also dead (6->4 dispatches moved total only ~2us).
// R13: R11 base + fuse x->bf16 cvt INTO gemm0's A-staging (fp32 float4 loads
//   -> v_cvt_pk_bf16_f32 -> ds_write, lane-linear dest unchanged); xb buffer
//   deleted (-48MB traffic incl. prep roundtrip); prep = weights only (4096
//   blocks). attn = R6 verbatim (90.5us); gemm1 unchanged; bounds (256,3).
// ---------------------------------------------------------------------------

typedef __bf16 bf16x8 __attribute__((ext_vector_type(8)));
typedef float f32x4 __attribute__((ext_vector_type(4)));
typedef unsigned int u32x4 __attribute__((ext_vector_type(4)));

#define DEV __device__ __forceinline__

DEV unsigned short f2b(float x) {          // fp32 -> bf16 RNE
  unsigned int u = __float_as_uint(x);
  u += 0x7fffu + ((u >> 16) & 1u);
  return (unsigned short)(u >> 16);
}

// two fp32 -> packed bf16 dword; compiler lowers pair to v_cvt_pk_bf16_f32
DEV unsigned int pk2(float a, float b) {
  union { __bf16 h[2]; unsigned int u; } c;
  c.h[0] = (__bf16)a;
  c.h[1] = (__bf16)b;
  return c.u;
}

#if __has_builtin(__builtin_amdgcn_exp2f)
DEV float exp2_fast(float x) { return __builtin_amdgcn_exp2f(x); }
#else
DEV float exp2_fast(float x) { return exp2f(x); }
#endif

// Cross-quad redistribution at fixed l15 (C/D accum layout -> B-operand
// layout). HW-verified R5/R6/R8/R9/R10/R11.
DEV void xpose_pair(unsigned int a, unsigned int b,
                    unsigned int& x, unsigned int& y) {
#if __has_builtin(__builtin_amdgcn_permlane32_swap) && \
    __has_builtin(__builtin_amdgcn_permlane16_swap)
  auto t = __builtin_amdgcn_permlane32_swap(a, b, false, false);
  auto u = __builtin_amdgcn_permlane16_swap(t[0], t[1], false, false);
  x = u[0];
  y = u[1];
#else
  int la = (int)(threadIdx.x & 63);
  unsigned int a32 = (unsigned int)__shfl_xor((int)a, 32, 64);
  unsigned int b32 = (unsigned int)__shfl_xor((int)b, 32, 64);
  unsigned int t0 = (la < 32) ? a : b32;     // {a[0:31], b[0:31]}
  unsigned int t1 = (la < 32) ? a32 : b;     // {a[32:63], b[32:63]}
  unsigned int t0x = (unsigned int)__shfl_xor((int)t0, 16, 64);
  unsigned int t1x = (unsigned int)__shfl_xor((int)t1, 16, 64);
  bool odd = ((la >> 4) & 1) != 0;
  x = odd ? t1x : t0;
  y = odd ? t1 : t0x;
#endif
}

DEV bf16x8 u4_to_bf(u32x4 v) {
  union { u32x4 u; bf16x8 b; } c;
  c.u = v;
  return c.b;
}

// async global->LDS, 16B per lane (unpadded lane-contiguous dest only).
DEV void g2l16(const void* g, void* l) {
  __builtin_amdgcn_global_load_lds(
      (const __attribute__((address_space(1))) unsigned int*)(unsigned long long)g,
      (__attribute__((address_space(3))) unsigned int*)(unsigned int)(unsigned long long)l,
      16, 0, 0);
}

// ---------------------------------------------------------------------------
// prep: weight transposes only. blocks [0,3072) Wqkv; [3072,4096) Wout.
// ---------------------------------------------------------------------------
__global__ void prep_w_kernel(const float* __restrict__ Wqkv,
                              unsigned short* __restrict__ wqt,
                              const float* __restrict__ Wout,
                              unsigned short* __restrict__ wot) {
  __shared__ float tile[32][33];
  const int bid = blockIdx.x;
  const int tid = threadIdx.x;
  const float* W;
  unsigned short* Wt;
  int bx, N;
  int by;
  if (bid < 3072) {                        // Wqkv: 96 x 32 tiles, N=3072
    W = Wqkv; Wt = wqt; N = 3072;
    bx = bid % 96; by = bid / 96;
  } else {                                 // Wout: 32 x 32 tiles, N=1024
    int b3 = bid - 3072;
    W = Wout; Wt = wot; N = 1024;
    bx = b3 % 32; by = b3 / 32;
  }
  const int K = 1024;
  int n0 = bx * 32, k0 = by * 32;
  int tx = tid & 31, ty = tid >> 5;        // (32, 8)
#pragma unroll
  for (int i = 0; i < 32; i += 8)
    tile[ty + i][tx] = W[(size_t)(k0 + ty + i) * N + n0 + tx];
  __syncthreads();
#pragma unroll
  for (int i = 0; i < 32; i += 8)
    Wt[(size_t)(n0 + ty + i) * K + k0 + tx] = f2b(tile[tx][ty + i]);
}

#define QSCALE 0.18033688011112042f   // 0.125 * log2(e): softmax in exp2 domain

// ---------------------------------------------------------------------------
// gemm0: C[8192,3072] = bf16(x) @ Wqkv^T + bias. m97 128x128, BK=32.
// A staged from fp32 x with in-register RNE cvt (fused prep); B via g2l16.
// Epilogue: cols 0..1023 -> Q (scaled), 1024..2047 -> K frag order,
// 2048..3071 -> V frag order.
// ---------------------------------------------------------------------------
__global__ __launch_bounds__(256, 3)
void gemm0_kernel(const float* __restrict__ X,
                  const unsigned short* __restrict__ Bt,
                  const float* __restrict__ bias,
                  unsigned short* __restrict__ qout,
                  unsigned short* __restrict__ kfrout,
                  unsigned short* __restrict__ vfrout) {
  constexpr int K = 1024;
  __shared__ unsigned short As[128 * 32];
  __shared__ unsigned short Bs[128 * 32];

  const int tid = threadIdx.x;
  const int lane = tid & 63;
  const int w = tid >> 6;
  const int wm = w & 1, wn = w >> 1;          // 2x2 wave grid, 64x64 per wave
  const int l15 = lane & 15, quad = lane >> 4;
  const int m0 = blockIdx.y * 128;
  const int n0 = blockIdx.x * 128;

  const float* Ax = X + (size_t)m0 * K;
  const unsigned short* Bg = Bt + (size_t)n0 * K;

  // chunk c (0..511): row=c/4, 16B bf16 part=c%4 ; LDS landing = c*16 bytes
  const int c0 = tid, c1 = tid + 256;
  const size_t gaf0 = (size_t)(c0 >> 2) * K + (size_t)(c0 & 3) * 8;  // fp32 elems
  const size_t gaf1 = (size_t)(c1 >> 2) * K + (size_t)(c1 & 3) * 8;
  const size_t gb0 = gaf0;                    // same element indexing for B
  const size_t gb1 = gaf1;

  f32x4 acc[4][4] = {};

  for (int kt = 0; kt < K; kt += 32) {
    g2l16(Bg + gb0 + kt, &Bs[c0 * 8]);        // B DMA first (async)
    g2l16(Bg + gb1 + kt, &Bs[c1 * 8]);
    // A: fp32 loads -> cvt_pk -> 16B LDS writes (lane-linear dest unchanged)
    float4 a0 = *(const float4*)(Ax + gaf0 + kt);
    float4 a1 = *(const float4*)(Ax + gaf0 + kt + 4);
    float4 a2 = *(const float4*)(Ax + gaf1 + kt);
    float4 a3 = *(const float4*)(Ax + gaf1 + kt + 4);
    u32x4 p0 = {pk2(a0.x, a0.y), pk2(a0.z, a0.w), pk2(a1.x, a1.y), pk2(a1.z, a1.w)};
    u32x4 p1 = {pk2(a2.x, a2.y), pk2(a2.z, a2.w), pk2(a3.x, a3.y), pk2(a3.z, a3.w)};
    *(u32x4*)&As[c0 * 8] = p0;
    *(u32x4*)&As[c1 * 8] = p1;
    __syncthreads();   // drains vmcnt (B DMA) + lgkm (A writes)
    bf16x8 af[4], bfr[4];
#pragma unroll
    for (int i = 0; i < 4; ++i) {
      af[i]  = *(const bf16x8*)&As[(wm * 64 + i * 16 + l15) * 32 + quad * 8];
      bfr[i] = *(const bf16x8*)&Bs[(wn * 64 + i * 16 + l15) * 32 + quad * 8];
    }
#pragma unroll
    for (int mi = 0; mi < 4; ++mi)
#pragma unroll
      for (int ni = 0; ni < 4; ++ni)
        acc[mi][ni] = __builtin_amdgcn_mfma_f32_16x16x32_bf16(
            af[mi], bfr[ni], acc[mi][ni], 0, 0, 0);
    __syncthreads();
  }

  float bv[4];
#pragma unroll
  for (int ni = 0; ni < 4; ++ni)
    bv[ni] = bias[n0 + wn * 64 + ni * 16 + l15];

  const int sel = n0 >> 10;                 // uniform per block (1024%128==0)
  const int bbat = m0 >> 11;                // batch index (uniform per block)
  const int ktb = ((m0 & 2047) >> 6) + wm;  // key-tile (uniform per wave)
  if (sel == 0) {                           // ---- Q ----
#pragma unroll
    for (int mi = 0; mi < 4; ++mi) {
      int rb = m0 + wm * 64 + mi * 16 + quad * 4;
#pragma unroll
      for (int ni = 0; ni < 4; ++ni) {
        int c = (n0 & 1023) + wn * 64 + ni * 16 + l15;   // h*64+d
#pragma unroll
        for (int r = 0; r < 4; ++r)
          qout[(size_t)(rb + r) * 1024 + c] =
              f2b((acc[mi][ni][r] + bv[ni]) * QSCALE);
      }
    }
  } else if (sel == 1) {                    // ---- K -> frag order ----
#pragma unroll
    for (int ni = 0; ni < 4; ++ni) {
      int c = (n0 & 1023) + wn * 64 + ni * 16 + l15;
      int h = c >> 6, d = c & 63;
      int kc = d >> 5, dq = (d >> 3) & 3, j = d & 7;
      size_t fb = ((((size_t)(bbat * 16 + h) * 32 + ktb) * 8) + kc) * 512 +
                  (size_t)(dq * 16) * 8 + j;
#pragma unroll
      for (int mi = 0; mi < 4; ++mi) {
        size_t fm = fb + (size_t)mi * 1024;   // +mi*2*512
#pragma unroll
        for (int r = 0; r < 4; ++r)
          kfrout[fm + (quad * 4 + r) * 8] = f2b(acc[mi][ni][r] + bv[ni]);
      }
    }
  } else {                                  // ---- V -> frag order ----
    const int fqb = quad >> 1;
    const int jj0 = (quad & 1) * 4;
#pragma unroll
    for (int ni = 0; ni < 4; ++ni) {
      int c = (n0 & 1023) + wn * 64 + ni * 16 + l15;
      int h = c >> 6, d = c & 63;
      int df = d >> 4, fl15 = d & 15;
#pragma unroll
      for (int mi = 0; mi < 4; ++mi) {
        int kc2 = mi >> 1;
        int fquad = (mi & 1) * 2 + fqb;
        size_t fb = ((((size_t)(bbat * 16 + h) * 32 + ktb) * 8) + df * 2 + kc2) * 512 +
                    (size_t)(fquad * 16 + fl15) * 8 + jj0;
        ushort4 pk;
        pk.x = f2b(acc[mi][ni][0] + bv[ni]);
        pk.y = f2b(acc[mi][ni][1] + bv[ni]);
        pk.z = f2b(acc[mi][ni][2] + bv[ni]);
        pk.w = f2b(acc[mi][ni][3] + bv[ni]);
        *(ushort4*)&vfrout[fb] = pk;
      }
    }
  }
}

// ---------------------------------------------------------------------------
// gemm1: out[8192,1024] = oat @ Wout^T + bout (fp32 out). m97 128x128.
// ---------------------------------------------------------------------------
__global__ __launch_bounds__(256, 3)
void gemm1_kernel(const unsigned short* __restrict__ A,
                  const unsigned short* __restrict__ Bt,
                  const float* __restrict__ bias,
                  float* __restrict__ fout) {
  constexpr int K = 1024;
  __shared__ unsigned short As[128 * 32];
  __shared__ unsigned short Bs[128 * 32];

  const int tid = threadIdx.x;
  const int lane = tid & 63;
  const int w = tid >> 6;
  const int wm = w & 1, wn = w >> 1;
  const int l15 = lane & 15, quad = lane >> 4;
  const int m0 = blockIdx.y * 128;
  const int n0 = blockIdx.x * 128;

  const unsigned short* Ag = A + (size_t)m0 * K;
  const unsigned short* Bg = Bt + (size_t)n0 * K;

  const int c0 = tid, c1 = tid + 256;
  const size_t ga0 = (size_t)(c0 >> 2) * K + (size_t)(c0 & 3) * 8;
  const size_t ga1 = (size_t)(c1 >> 2) * K + (size_t)(c1 & 3) * 8;

  f32x4 acc[4][4] = {};

  for (int kt = 0; kt < K; kt += 32) {
    g2l16(Ag + ga0 + kt, &As[c0 * 8]);
    g2l16(Ag + ga1 + kt, &As[c1 * 8]);
    g2l16(Bg + ga0 + kt, &Bs[c0 * 8]);
    g2l16(Bg + ga1 + kt, &Bs[c1 * 8]);
    __syncthreads();
    bf16x8 af[4], bfr[4];
#pragma unroll
    for (int i = 0; i < 4; ++i) {
      af[i]  = *(const bf16x8*)&As[(wm * 64 + i * 16 + l15) * 32 + quad * 8];
      bfr[i] = *(const bf16x8*)&Bs[(wn * 64 + i * 16 + l15) * 32 + quad * 8];
    }
#pragma unroll
    for (int mi = 0; mi < 4; ++mi)
#pragma unroll
      for (int ni = 0; ni < 4; ++ni)
        acc[mi][ni] = __builtin_amdgcn_mfma_f32_16x16x32_bf16(
            af[mi], bfr[ni], acc[mi][ni], 0, 0, 0);
    __syncthreads();
  }

  float bv[4];
#pragma unroll
  for (int ni = 0; ni < 4; ++ni)
    bv[ni] = bias[n0 + wn * 64 + ni * 16 + l15];

#pragma unroll
  for (int mi = 0; mi < 4; ++mi) {
    int rb = m0 + wm * 64 + mi * 16 + quad * 4;
#pragma unroll
    for (int ni = 0; ni < 4; ++ni) {
      int c = n0 + wn * 64 + ni * 16 + l15;
#pragma unroll
      for (int r = 0; r < 4; ++r)
        fout[(size_t)(rb + r) * 1024 + c] = acc[mi][ni][r] + bv[ni];
    }
  }
}

// ---------------------------------------------------------------------------
// Flash attention (R6 verbatim, 90.5us). 4 waves x 32 q/wave = 128 q/block;
// 1024 blocks = 4/CU. K/V frag tiles double-buffered in LDS via g2l16,
// one barrier per tile; P relayout via permlane. Exact (bounded scores).
// ---------------------------------------------------------------------------
__global__ __launch_bounds__(256, 4)
void attn_kernel(const unsigned short* __restrict__ qg,
                 const unsigned short* __restrict__ kfr,
                 const unsigned short* __restrict__ vfr,
                 unsigned short* __restrict__ oat) {
  __shared__ unsigned short Ks[2][4096];   // 8KB per buf
  __shared__ unsigned short Vs[2][4096];

  const int tid = threadIdx.x;
  const int lane = tid & 63;
  const int w = tid >> 6;
  const int l15 = lane & 15, quad = lane >> 4;

  // XCD swizzle: grid (8, 128); head = bx*8+(by>>4): 8 heads/XCD -> 4MB L2.
  const int head = blockIdx.x * 8 + (blockIdx.y >> 4);
  const int q0 = (blockIdx.y & 15) * 128;
  const int b = head >> 4, h = head & 15;
  const size_t tokbase = (size_t)b * 2048;

  bf16x8 qf[2][2];
#pragma unroll
  for (int nj = 0; nj < 2; ++nj)
#pragma unroll
    for (int kc = 0; kc < 2; ++kc) {
      int q = q0 + w * 32 + nj * 16 + l15;
      qf[nj][kc] = *(const bf16x8*)(qg + (tokbase + q) * 1024 + h * 64 +
                                    kc * 32 + quad * 8);
    }

  f32x4 oacc[4][2] = {};                    // O^T frags [df][nj], 32 regs
  float lsum[2] = {0.f, 0.f};

  const unsigned short* kpb = kfr + (size_t)head * 32 * 4096;
  const unsigned short* vpb = vfr + (size_t)head * 32 * 4096;

  auto stage = [&](int buf, int kt2) {
    const unsigned short* ks = kpb + (size_t)kt2 * 4096;
    const unsigned short* vs = vpb + (size_t)kt2 * 4096;
    g2l16(ks + (size_t)tid * 8,         &Ks[buf][tid * 8]);
    g2l16(ks + (size_t)(tid + 256) * 8, &Ks[buf][(tid + 256) * 8]);
    g2l16(vs + (size_t)tid * 8,         &Vs[buf][tid * 8]);
    g2l16(vs + (size_t)(tid + 256) * 8, &Vs[buf][(tid + 256) * 8]);
  };

  stage(0, 0);

  for (int kt = 0; kt < 32; ++kt) {
    const int cur = kt & 1;
    __syncthreads();                  // buf[cur] staged (drains vmcnt)
    if (kt < 31) stage(cur ^ 1, kt + 1);   // in flight across this tile

    // ---- S^T = K Q^T (frag reads streamed per kc) ----
    const unsigned short* Kb = Ks[cur];
    f32x4 st[2][4];                   // [nj][mi]
#pragma unroll
    for (int nj = 0; nj < 2; ++nj)
#pragma unroll
      for (int mi = 0; mi < 4; ++mi)
        st[nj][mi] = (f32x4){0.f, 0.f, 0.f, 0.f};
#pragma unroll
    for (int kc = 0; kc < 2; ++kc) {
      bf16x8 kf4[4];
#pragma unroll
      for (int mi = 0; mi < 4; ++mi)
        kf4[mi] = *(const bf16x8*)&Kb[(mi * 2 + kc) * 512 + lane * 8];
      __builtin_amdgcn_s_setprio(1);
#pragma unroll
      for (int mi = 0; mi < 4; ++mi)
#pragma unroll
        for (int nj = 0; nj < 2; ++nj)
          st[nj][mi] = __builtin_amdgcn_mfma_f32_16x16x32_bf16(
              kf4[mi], qf[nj][kc], st[nj][mi], 0, 0, 0);
      __builtin_amdgcn_s_setprio(0);
    }

    // ---- softmax (exp2 domain) + in-register C/D -> B-operand relayout ----
    bf16x8 pf2[2][2];
#pragma unroll
    for (int nj = 0; nj < 2; ++nj) {
      float rs = 0.f;
      unsigned int s0[4], s1[4];   // s0[mi]=keys mi*16+quad*4+{0,1}, s1 +{2,3}
#pragma unroll
      for (int mi = 0; mi < 4; ++mi) {
        float p0 = exp2_fast(st[nj][mi][0]);
        float p1 = exp2_fast(st[nj][mi][1]);
        float p2 = exp2_fast(st[nj][mi][2]);
        float p3 = exp2_fast(st[nj][mi][3]);
        rs += (p0 + p1) + (p2 + p3);
        s0[mi] = pk2(p0, p1);
        s1[mi] = pk2(p2, p3);
      }
      lsum[nj] += rs;
      unsigned int o00, o01, o02, o03, o10, o11, o12, o13;
      xpose_pair(s0[0], s0[1], o00, o02);
      xpose_pair(s1[0], s1[1], o01, o03);
      xpose_pair(s0[2], s0[3], o10, o12);
      xpose_pair(s1[2], s1[3], o11, o13);
      u32x4 t0 = {o00, o01, o02, o03};
      u32x4 t1 = {o10, o11, o12, o13};
      pf2[nj][0] = u4_to_bf(t0);
      pf2[nj][1] = u4_to_bf(t1);
    }

    // ---- O^T += V^T P^T (frag reads streamed per kc) ----
    const unsigned short* Vb = Vs[cur];
#pragma unroll
    for (int kc = 0; kc < 2; ++kc) {
      bf16x8 vf4[4];
#pragma unroll
      for (int df = 0; df < 4; ++df)
        vf4[df] = *(const bf16x8*)&Vb[(df * 2 + kc) * 512 + lane * 8];
      __builtin_amdgcn_s_setprio(1);
#pragma unroll
      for (int df = 0; df < 4; ++df)
#pragma unroll
        for (int nj = 0; nj < 2; ++nj)
          oacc[df][nj] = __builtin_amdgcn_mfma_f32_16x16x32_bf16(
              vf4[df], pf2[nj][kc], oacc[df][nj], 0, 0, 0);
      __builtin_amdgcn_s_setprio(0);
    }
  }

  // epilogue: cross-quad sum (once), divide, pack, store
#pragma unroll
  for (int nj = 0; nj < 2; ++nj) {
    float s = lsum[nj];
    s += __shfl_xor(s, 16, 64);
    s += __shfl_xor(s, 32, 64);
    float inv = __builtin_amdgcn_rcpf(s);
    int q = q0 + w * 32 + nj * 16 + l15;
#pragma unroll
    for (int df = 0; df < 4; ++df) {
      uint2 pw;
      pw.x = pk2(oacc[df][nj][0] * inv, oacc[df][nj][1] * inv);
      pw.y = pk2(oacc[df][nj][2] * inv, oacc[df][nj][3] * inv);
      *(uint2*)&oat[(tokbase + q) * 1024 + h * 64 + df * 16 + quad * 4] = pw;
    }
  }
}

// ---------------------------------------------------------------------------
// launch
// ---------------------------------------------------------------------------
extern "C" void kernel_launch(void* const* d_in, const int* in_sizes, int n_in,
                              void* d_out, int out_size, void* d_ws, size_t ws_size,
                              hipStream_t stream) {
  const float* x    = (const float*)d_in[0];   // [4,2048,1024]
  const float* Wqkv = (const float*)d_in[1];   // [1024,3072]
  const float* bqkv = (const float*)d_in[2];   // [3072]
  const float* Wout = (const float*)d_in[3];   // [1024,1024]
  const float* bout = (const float*)d_in[4];   // [1024]
  float* out = (float*)d_out;                  // [4,2048,1024] fp32

  char* ws = (char*)d_ws;
  unsigned short* wqt = (unsigned short*)(ws + (size_t)0);          //  6 MiB
  unsigned short* wot = (unsigned short*)(ws + ((size_t)6 << 20));  //  2 MiB
  unsigned short* qbf = (unsigned short*)(ws + ((size_t)8 << 20));  // 16 MiB
  unsigned short* kfr = (unsigned short*)(ws + ((size_t)24 << 20)); // 16 MiB
  unsigned short* vfr = (unsigned short*)(ws + ((size_t)40 << 20)); // 16 MiB
  unsigned short* oat = (unsigned short*)(ws + ((size_t)56 << 20)); // 16 MiB

  prep_w_kernel<<<4096, 256, 0, stream>>>(Wqkv, wqt, Wout, wot);

  gemm0_kernel<<<dim3(24, 64), 256, 0, stream>>>(
      x, wqt, bqkv, qbf, kfr, vfr);

  attn_kernel<<<dim3(8, 128), 256, 0, stream>>>(qbf, kfr, vfr, oat);

  gemm1_kernel<<<dim3(8, 64), 256, 0, stream>>>(oat, wot, bout, out);
}